// Round 8
// baseline (199.470 us; speedup 1.0000x reference)
//
#include <hip/hip_runtime.h>

#define NBINS 256
constexpr int W_IMG = 512;
constexpr int H_IMG = 512;
constexpr int IMG_ELEMS = H_IMG * W_IMG;          // 262144
constexpr int PAIR_ROWS = H_IMG - 1;              // 511 (pair rows 0..510)
constexpr int NIMG = 96;
constexpr int HIST = NBINS * NBINS;               // 65536
constexpr int WORDS_PER_IMG = HIST / 2;           // 32768 packed u32 = 128 KB
constexpr int QI = 1024;                          // fixed-point scale (validated R2-R6)
constexpr int PF = 8;                             // prefetch ring depth (float2 rows)

// cos(pi*d): v_cos_f32 takes revolutions -> cos(2*pi*x), x = d/2 in [0,0.5].
__device__ __forceinline__ float cospi_fast(float d) {
    return __builtin_amdgcn_cosf(0.5f * d);
}

struct Q { int i0, q0; };  // floor bin (0..254), w0 quantized to 1024

__device__ __forceinline__ Q quant(float x) {
    float fa = floorf(x);
    Q e;
    e.i0 = (int)fa;
    e.q0 = (int)(cospi_fast(x - fa) * 512.0f + 512.5f);  // round(1024*w0)
    return e;
}

// Emit one pair (a over rows, b over cols) into the packed u16 hist.
// Complement trick: p01 = q0-p00, p11 = qa1-p10 (mass-exact, 2 muls total).
// Merged atomics: bins (i,i+1) share a u32 word when i is even -> 2 ds_adds.
__device__ __forceinline__ void emit(unsigned* __restrict__ lh, Q a, Q b) {
    int qa1 = QI - a.q0;
    unsigned p00 = (unsigned)(a.q0 * b.q0 + QI / 2) >> 10;
    unsigned p01 = (unsigned)a.q0 - p00;
    unsigned p10 = (unsigned)(qa1 * b.q0 + QI / 2) >> 10;
    unsigned p11 = (unsigned)qa1 - p10;
    unsigned w0 = ((unsigned)a.i0 << 7) + ((unsigned)b.i0 >> 1);  // row*128 + col/2
    unsigned w1 = w0 + 128u;                                      // next a-row
    if (b.i0 & 1) {            // bins i (hi half of w), i+1 (lo half of w+1)
        atomicAdd(&lh[w0], p00 << 16);
        atomicAdd(&lh[w0 + 1], p01);
        atomicAdd(&lh[w1], p10 << 16);
        atomicAdd(&lh[w1 + 1], p11);
    } else {                   // bins i, i+1 in the SAME word: one add each row
        atomicAdd(&lh[w0], p00 | (p01 << 16));
        atomicAdd(&lh[w1], p10 | (p11 << 16));
    }
}

// ---------- hist: GROUPS=1, full 128 KB dynamic-LDS histogram ----------
// Block (s, bc): pair-rows [rb,re) of image bc. 1024 threads: each owns TWO
// adjacent columns (float2 loads), sub = tid>>8 quarters the row range (waves
// stay sub-uniform). Depth-8 float2 prefetch ring; each element quantized once.
__global__ __launch_bounds__(1024, 1)
void hist1_kernel(const float* __restrict__ X, unsigned* __restrict__ ws) {
    extern __shared__ unsigned lh[];              // 32768 words = 128 KB
    const int tid = threadIdx.x;
    const int s = blockIdx.x;
    const int bc = blockIdx.y;
    const int S = gridDim.x;
    const float2* col = reinterpret_cast<const float2*>(X + (size_t)bc * IMG_ELEMS)
                        + (tid & 255);            // float2-column, stride 256/row

    {
        uint4* lv = reinterpret_cast<uint4*>(lh);
        for (int i = tid; i < WORDS_PER_IMG / 4; i += 1024)
            lv[i] = make_uint4(0u, 0u, 0u, 0u);
    }
    __syncthreads();

    const int rb = (PAIR_ROWS * s) / S;
    const int re = (PAIR_ROWS * (s + 1)) / S;
    const int l = (re - rb + 3) >> 2;
    const int sub = tid >> 8;                     // 0..3, wave-uniform
    const int r0t = rb + sub * l;
    const int r1t = min(re, r0t + l);

    float2 cur[PF], nxt[PF];
#pragma unroll
    for (int j = 0; j < PF; ++j)
        cur[j] = col[(size_t)min(r0t + 1 + j, PAIR_ROWS) * (W_IMG / 2)];
    float2 first = col[(size_t)min(r0t, PAIR_ROWS) * (W_IMG / 2)];
    Q ax = quant(first.x), ay = quant(first.y);

    for (int R = r0t; R < r1t; R += PF) {
#pragma unroll
        for (int j = 0; j < PF; ++j)
            nxt[j] = col[(size_t)min(R + PF + 1 + j, PAIR_ROWS) * (W_IMG / 2)];
#pragma unroll
        for (int j = 0; j < PF; ++j) {
            if (R + j < r1t) {                    // wave-uniform guard
                Q bx = quant(cur[j].x);
                Q by = quant(cur[j].y);
                emit(lh, ax, bx);
                emit(lh, ay, by);
                ax = bx; ay = by;
            }
        }
#pragma unroll
        for (int j = 0; j < PF; ++j) cur[j] = nxt[j];
    }
    __syncthreads();

    unsigned* dst = ws + ((size_t)s * NIMG + bc) * WORDS_PER_IMG;
    const uint4* sv = reinterpret_cast<const uint4*>(lh);
    uint4* dv = reinterpret_cast<uint4*>(dst);
    for (int i = tid; i < WORDS_PER_IMG / 4; i += 1024) dv[i] = sv[i];
}

// ---------- tail 1: sum slices IN-PLACE into slice 0 + per-quarter max ----------
// Grid (4, 96): block sums its 8192-word quarter across S slices (read-then-write
// slice 0, disjoint words per thread -> no hazard), reduces the quarter max.
__global__ __launch_bounds__(1024)
void summax_kernel(unsigned* __restrict__ ws, float* __restrict__ partial, int S) {
    const int q = blockIdx.x, bc = blockIdx.y, tid = threadIdx.x;
    const size_t base = (size_t)bc * WORDS_PER_IMG + (size_t)q * 8192;
    uint4* s0 = reinterpret_cast<uint4*>(ws + base);
    unsigned m = 0u;
#pragma unroll
    for (int k = 0; k < 2; ++k) {
        const int i = tid + k * 1024;
        uint4 v = s0[i];
        for (int s = 1; s < S; ++s) {
            const uint4* sp = reinterpret_cast<const uint4*>(
                ws + (size_t)s * NIMG * WORDS_PER_IMG + base);
            uint4 u = sp[i];
            v.x += u.x; v.y += u.y; v.z += u.z; v.w += u.w;
        }
        s0[i] = v;
        m = max(m, max(max(v.x & 0xFFFFu, v.x >> 16), max(v.y & 0xFFFFu, v.y >> 16)));
        m = max(m, max(max(v.z & 0xFFFFu, v.z >> 16), max(v.w & 0xFFFFu, v.w >> 16)));
    }
#pragma unroll
    for (int off = 32; off > 0; off >>= 1)
        m = max(m, (unsigned)__shfl_down((int)m, off, 64));
    __shared__ unsigned sm[16];
    if ((tid & 63) == 0) sm[tid >> 6] = m;
    __syncthreads();
    if (tid == 0) {
        unsigned mm = sm[0];
#pragma unroll
        for (int i = 1; i < 16; ++i) mm = max(mm, sm[i]);
        partial[bc * 4 + q] = (float)mm;
    }
}

// ---------- tail 2: normalize (quant scale cancels in the ratio) ----------
__global__ __launch_bounds__(1024)
void norm_kernel(const unsigned* __restrict__ ws, const float* __restrict__ partial,
                 float* __restrict__ out) {
    const int q = blockIdx.x, bc = blockIdx.y, tid = threadIdx.x;
    const float inv = 1.0f / fmaxf(fmaxf(partial[bc * 4 + 0], partial[bc * 4 + 1]),
                                   fmaxf(partial[bc * 4 + 2], partial[bc * 4 + 3]));
    const size_t base = (size_t)bc * WORDS_PER_IMG + (size_t)q * 8192;
    const uint4* s0 = reinterpret_cast<const uint4*>(ws + base);
    float4* o = reinterpret_cast<float4*>(out + (size_t)bc * HIST + (size_t)q * 16384);
#pragma unroll
    for (int k = 0; k < 2; ++k) {
        const int i = tid + k * 1024;
        uint4 v = s0[i];
        float4 f0 = make_float4((float)(v.x & 0xFFFFu) * inv, (float)(v.x >> 16) * inv,
                                (float)(v.y & 0xFFFFu) * inv, (float)(v.y >> 16) * inv);
        float4 f1 = make_float4((float)(v.z & 0xFFFFu) * inv, (float)(v.z >> 16) * inv,
                                (float)(v.w & 0xFFFFu) * inv, (float)(v.w >> 16) * inv);
        o[2 * i] = f0;
        o[2 * i + 1] = f1;
    }
}

extern "C" void kernel_launch(void* const* d_in, const int* in_sizes, int n_in,
                              void* d_out, int out_size, void* d_ws, size_t ws_size,
                              hipStream_t stream) {
    const float* X = (const float*)d_in[0];
    float* out = (float*)d_out;
    unsigned* ws = (unsigned*)d_ws;

    const size_t slice_bytes = (size_t)NIMG * WORDS_PER_IMG * sizeof(unsigned); // 12 MB
    int S = 8;
    while (S > 1 && (size_t)S * slice_bytes + 16384 > ws_size) S >>= 1;
    float* partial = (float*)((char*)d_ws + (size_t)S * slice_bytes);  // 384 floats

    // 128 KB dynamic LDS opt-in (host-side, graph-capture-safe; proven in R6).
    (void)hipFuncSetAttribute(reinterpret_cast<const void*>(hist1_kernel),
                              hipFuncAttributeMaxDynamicSharedMemorySize,
                              WORDS_PER_IMG * 4);

    hist1_kernel<<<dim3(S, NIMG), 1024, WORDS_PER_IMG * 4, stream>>>(X, ws);
    summax_kernel<<<dim3(4, NIMG), 1024, 0, stream>>>(ws, partial, S);
    norm_kernel<<<dim3(4, NIMG), 1024, 0, stream>>>(ws, partial, out);
}